// Round 8
// baseline (130.061 us; speedup 1.0000x reference)
//
#include <hip/hip_runtime.h>

#define EPS 1e-5f
#define MAGIC 0x5CA9F1A6u

typedef float v2f __attribute__((ext_vector_type(2)));

// Fast reciprocal: single v_rcp_f32 (~1 ulp) instead of IEEE div sequence.
__device__ __forceinline__ float frcp(float x) { return __builtin_amdgcn_rcpf(x); }
__device__ __forceinline__ float fsigm(float x) { return frcp(1.0f + __expf(-x)); }
__device__ __forceinline__ float ftanh(float x) {
    float e = __expf(-2.0f * x);
    return (1.0f - e) * frcp(1.0f + e);
}
// uniform broadcast of lane k's value -> SGPR (k compile-time constant)
__device__ __forceinline__ float rdl(float v, int k) {
    return __int_as_float(__builtin_amdgcn_readlane(__float_as_int(v), k));
}

// ---------------------------------------------------------------------------
// Single launch. Blocks 0..59: per-frame frontend (proven body) -> Gx ->
// threadfence -> release flag. Block 60: stage w_hh while frontends run,
// parallel-poll the flags, then the scan.
// Scan layout (NEW): lane j owns cell m=j&31 and computes ALL FOUR gate dot
// products (w_hh rows m,32+m,64+m,96+m packed as two v2f arrays). The whole
// recurrence c=sigm(f)c+sigm(i)tanh(g), h=sigm(o)tanh(c) is per-lane:
// ZERO cross-lane ops on the serial chain (R5/R7 evidence: the cross-half
// shfl/bpermute was a ~100+cyc/step chain tax). h broadcast via v_readlane.
// ---------------------------------------------------------------------------
__global__ __launch_bounds__(64) void fused_kernel(
    const float* __restrict__ x,
    const float* __restrict__ w00, const float* __restrict__ b00,
    const float* __restrict__ w01, const float* __restrict__ b01,
    const float* __restrict__ ln_g, const float* __restrict__ ln_b,
    const float* __restrict__ w_ih, const float* __restrict__ w_hh,
    const float* __restrict__ b_ih, const float* __restrict__ b_hh,
    const float* __restrict__ bn_g, const float* __restrict__ bn_b,
    const float* __restrict__ w10, const float* __restrict__ b10,
    const float* __restrict__ w11, const float* __restrict__ b11,
    const float* __restrict__ w12, const float* __restrict__ b12,
    float* __restrict__ Gx, unsigned* __restrict__ flags,
    float* __restrict__ out)
{
    __shared__ float smem[16324];
    const int j = threadIdx.x;

    if (blockIdx.x < 60) {
        // ------------------- frontend (proven round-1 body) -------------------
        const int t = blockIdx.x;
        float* w00s = smem;          // [63*63] rows stride 63 (conflict-free)
        float* w01s = smem + 3972;   // [64*63]
        float* wihT = smem + 8004;   // [64][128] transposed w_ih
        float* scr  = smem + 16196;  // [128]

        {
            const float4* g4 = (const float4*)w00;
            float4* s4 = (float4*)w00s;
            for (int i = j; i < 992; i += 64) s4[i] = g4[i];
            if (j == 0) w00s[3968] = w00[3968];
        }
        {
            const float4* g4 = (const float4*)w01;
            float4* s4 = (float4*)w01s;
            for (int i = j; i < 1008; i += 64) s4[i] = g4[i];
        }
        for (int r = j; r < 128; r += 64) {
            const float4* row = (const float4*)(w_ih + r * 64);
            #pragma unroll
            for (int q = 0; q < 16; q++) {
                float4 v = row[q];
                wihT[(4 * q + 0) * 128 + r] = v.x;
                wihT[(4 * q + 1) * 128 + r] = v.y;
                wihT[(4 * q + 2) * 128 + r] = v.z;
                wihT[(4 * q + 3) * 128 + r] = v.w;
            }
        }
        scr[j] = (j < 63) ? x[t * 63 + j] : 0.0f;
        __syncthreads();

        float f0 = 0.0f;
        if (j < 63) {
            float acc = b00[j];
            const float* wr = w00s + j * 63;
            #pragma unroll
            for (int k = 0; k < 63; k++) acc += scr[k] * wr[k];
            f0 = fmaxf(acc, 0.0f);
        }
        __syncthreads();
        scr[j] = f0;
        __syncthreads();

        float acc = b01[j];
        {
            const float* wr = w01s + j * 63;
            #pragma unroll
            for (int k = 0; k < 63; k++) acc += scr[k] * wr[k];
        }
        float f1 = fmaxf(acc, 0.0f);

        float s = f1, sq = f1 * f1;
        #pragma unroll
        for (int off = 32; off > 0; off >>= 1) {
            s  += __shfl_xor(s, off);
            sq += __shfl_xor(sq, off);
        }
        float mu  = s * (1.0f / 64.0f);
        float var = sq * (1.0f / 64.0f) - mu * mu;
        float f   = (f1 - mu) * rsqrtf(var + EPS) * ln_g[j] + ln_b[j];
        __syncthreads();
        scr[64 + j] = f;
        __syncthreads();

        float a0 = b_ih[j] + b_hh[j];
        float a1 = b_ih[j + 64] + b_hh[j + 64];
        #pragma unroll
        for (int k = 0; k < 64; k++) {
            float fk = scr[64 + k];
            a0 += fk * wihT[k * 128 + j];
            a1 += fk * wihT[k * 128 + 64 + j];
        }
        Gx[t * 128 + j]      = a0;
        Gx[t * 128 + 64 + j] = a1;

        __threadfence();
        __syncthreads();
        if (j == 0)
            __hip_atomic_store(&flags[t], MAGIC, __ATOMIC_RELEASE,
                               __HIP_MEMORY_SCOPE_AGENT);
        return;
    }

    // --------------------------- scan block (1 wave) ---------------------------
    float* gxs = smem;  // [61*128] (frame 60 = pad for prefetch)
    const int m = j & 31;  // cell index; high lanes replicate (harmless)

    // Stage ALL FOUR w_hh rows of cell m into VGPRs (overlaps frontend).
    // Gate order (jnp.split): i=rows 0:32, f=32:64, g=64:96, o=96:128.
    v2f wIF[32], wGO[32];
    {
        const float4* ri = (const float4*)(w_hh + (     m) * 32);
        const float4* rf = (const float4*)(w_hh + (32 + m) * 32);
        const float4* rg = (const float4*)(w_hh + (64 + m) * 32);
        const float4* ro = (const float4*)(w_hh + (96 + m) * 32);
        #pragma unroll
        for (int q = 0; q < 8; q++) {
            float4 vi = ri[q], vf = rf[q], vg = rg[q], vo = ro[q];
            wIF[4 * q + 0] = (v2f){vi.x, vf.x};  wGO[4 * q + 0] = (v2f){vg.x, vo.x};
            wIF[4 * q + 1] = (v2f){vi.y, vf.y};  wGO[4 * q + 1] = (v2f){vg.y, vo.y};
            wIF[4 * q + 2] = (v2f){vi.z, vf.z};  wGO[4 * q + 2] = (v2f){vg.z, vo.z};
            wIF[4 * q + 3] = (v2f){vi.w, vf.w};  wGO[4 * q + 3] = (v2f){vg.w, vo.w};
        }
    }

    // Parallel poll: lane t watches flags[t] (relaxed agent load), one ballot
    // per sweep; single acquire for ordering. Poison != MAGIC re-arms replays.
    {
        bool done = (j >= 60);
        while (true) {
            if (!done)
                done = (__hip_atomic_load(&flags[j], __ATOMIC_RELAXED,
                                          __HIP_MEMORY_SCOPE_AGENT) == MAGIC);
            if (__ballot(done) == ~0ULL) break;
            __builtin_amdgcn_s_sleep(1);
        }
        (void)__hip_atomic_load(&flags[0], __ATOMIC_ACQUIRE,
                                __HIP_MEMORY_SCOPE_AGENT);
    }

    // stage Gx -> LDS (1920 float4) + zero pad frame
    {
        const float4* g4 = (const float4*)Gx;
        float4* s4 = (float4*)gxs;
        for (int i = j; i < 1920; i += 64) s4[i] = g4[i];
        gxs[7680 + j] = 0.0f;
        gxs[7744 + j] = 0.0f;
    }
    __syncthreads();

    float c = 0.0f, hn = 0.0f;
    // prefetched gate inputs for this cell's four rows
    float gi = gxs[m], gf = gxs[32 + m], gg = gxs[64 + m], go = gxs[96 + m];
    for (int t = 0; t < 60; t++) {
        float hk[32];
        #pragma unroll
        for (int k = 0; k < 32; k++) hk[k] = rdl(hn, k);

        v2f aIF0 = {gi, gf}, aIF1 = {0.f, 0.f}, aIF2 = {0.f, 0.f}, aIF3 = {0.f, 0.f};
        v2f aGO0 = {gg, go}, aGO1 = {0.f, 0.f}, aGO2 = {0.f, 0.f}, aGO3 = {0.f, 0.f};
        // prefetch next frame's inputs (independent of recurrence)
        gi = gxs[(t + 1) * 128 +      m];
        gf = gxs[(t + 1) * 128 + 32 + m];
        gg = gxs[(t + 1) * 128 + 64 + m];
        go = gxs[(t + 1) * 128 + 96 + m];
        #pragma unroll
        for (int d = 0; d < 8; d++) {
            int k = d * 4;
            v2f h0 = {hk[k + 0], hk[k + 0]};
            v2f h1 = {hk[k + 1], hk[k + 1]};
            v2f h2 = {hk[k + 2], hk[k + 2]};
            v2f h3 = {hk[k + 3], hk[k + 3]};
            aIF0 += h0 * wIF[k + 0];  aGO0 += h0 * wGO[k + 0];
            aIF1 += h1 * wIF[k + 1];  aGO1 += h1 * wGO[k + 1];
            aIF2 += h2 * wIF[k + 2];  aGO2 += h2 * wGO[k + 2];
            aIF3 += h3 * wIF[k + 3];  aGO3 += h3 * wGO[k + 3];
        }
        v2f aIF = (aIF0 + aIF1) + (aIF2 + aIF3);
        v2f aGO = (aGO0 + aGO1) + (aGO2 + aGO3);

        // per-lane LSTM cell -- no cross-lane ops on the chain
        float si = fsigm(aIF.x);
        float sf = fsigm(aIF.y);
        float tg = ftanh(aGO.x);
        float so = fsigm(aGO.y);
        c  = sf * c + si * tg;
        hn = so * ftanh(c);       // valid on ALL lanes (m = j&31)
    }

    // Head (h read from low lanes; lanes >=32 replicate rows 0..31)
    const float rs = rsqrtf(1.0f + EPS);
    const int ro = j & 31;
    float acc = b10[ro];
    #pragma unroll
    for (int k = 0; k < 32; k++) {
        float hkk = rdl(hn, k);
        float hb = hkk * rs * bn_g[k] + bn_b[k];
        acc += w10[ro * 32 + k] * hb;
    }
    float o1 = fmaxf(acc, 0.0f);

    acc = b11[ro];
    #pragma unroll
    for (int k = 0; k < 32; k++) acc += w11[ro * 32 + k] * rdl(o1, k);
    float o2 = fmaxf(acc, 0.0f);

    float a[4];
    #pragma unroll
    for (int r = 0; r < 4; r++) a[r] = b12[j + 64 * r];
    #pragma unroll
    for (int k = 0; k < 32; k++) {
        float h2 = rdl(o2, k);
        #pragma unroll
        for (int r = 0; r < 4; r++) a[r] += w12[(j + 64 * r) * 32 + k] * h2;
    }
    #pragma unroll
    for (int r = 0; r < 4; r++) out[j + 64 * r] = a[r];
}

extern "C" void kernel_launch(void* const* d_in, const int* in_sizes, int n_in,
                              void* d_out, int out_size, void* d_ws, size_t ws_size,
                              hipStream_t stream) {
    const float* x    = (const float*)d_in[0];
    const float* w00  = (const float*)d_in[1];
    const float* b00  = (const float*)d_in[2];
    const float* w01  = (const float*)d_in[3];
    const float* b01  = (const float*)d_in[4];
    const float* ln_g = (const float*)d_in[5];
    const float* ln_b = (const float*)d_in[6];
    const float* w_ih = (const float*)d_in[7];
    const float* w_hh = (const float*)d_in[8];
    const float* b_ih = (const float*)d_in[9];
    const float* b_hh = (const float*)d_in[10];
    const float* bn_g = (const float*)d_in[11];
    const float* bn_b = (const float*)d_in[12];
    const float* w10  = (const float*)d_in[13];
    const float* b10  = (const float*)d_in[14];
    const float* w11  = (const float*)d_in[15];
    const float* b11  = (const float*)d_in[16];
    const float* w12  = (const float*)d_in[17];
    const float* b12  = (const float*)d_in[18];
    float* out = (float*)d_out;
    float*    Gx    = (float*)d_ws;                       // 30,720 B
    unsigned* flags = (unsigned*)((char*)d_ws + 49152);   // 60 flags

    fused_kernel<<<61, 64, 0, stream>>>(x, w00, b00, w01, b01, ln_g, ln_b,
                                        w_ih, w_hh, b_ih, b_hh, bn_g, bn_b,
                                        w10, b10, w11, b11, w12, b12,
                                        Gx, flags, out);
}

// Round 10
// 126.074 us; speedup vs baseline: 1.0316x; 1.0316x over previous
//
#include <hip/hip_runtime.h>

#define EPS 1e-5f
#define MAGIC 0x5CA9F1A6u

typedef float v2f __attribute__((ext_vector_type(2)));
// NOTE: amdgcn builtins (cvt_pkrtz, fdot2) use __fp16 vectors, not _Float16.
typedef __fp16 h2v2 __attribute__((ext_vector_type(2)));

// Fast reciprocal: single v_rcp_f32 (~1 ulp) instead of IEEE div sequence.
__device__ __forceinline__ float frcp(float x) { return __builtin_amdgcn_rcpf(x); }
__device__ __forceinline__ float fsigm(float x) { return frcp(1.0f + __expf(-x)); }
__device__ __forceinline__ float ftanh(float x) {
    float e = __expf(-2.0f * x);
    return (1.0f - e) * frcp(1.0f + e);
}
// uniform broadcast of lane k's value -> SGPR (k compile-time constant)
__device__ __forceinline__ int rdli(int v, int k) {
    return __builtin_amdgcn_readlane(v, k);
}
__device__ __forceinline__ float rdl32(float v, int k) {
    return __int_as_float(__builtin_amdgcn_readlane(__float_as_int(v), 32 + k));
}
// Sum of lane m and lane m+32's values, replicated to both halves (semantics-
// agnostic use of permlane32_swap: sum of both outputs = x[m]+x[m+32]).
__device__ __forceinline__ float xhalf_sum(float x) {
#if __has_builtin(__builtin_amdgcn_permlane32_swap)
    auto r = __builtin_amdgcn_permlane32_swap(__float_as_uint(x),
                                              __float_as_uint(x), false, false);
    return __uint_as_float(r[0]) + __uint_as_float(r[1]);
#else
    return x + __shfl_xor(x, 32);
#endif
}
// 2-way f16 dot with f32 accumulate: v_dot2_f32_f16 (2 MACs / instruction)
__device__ __forceinline__ float fdot2(h2v2 a, h2v2 b, float c) {
#if __has_builtin(__builtin_amdgcn_fdot2)
    return __builtin_amdgcn_fdot2(a, b, c, false);
#else
    return c + (float)a.x * (float)b.x + (float)a.y * (float)b.y;
#endif
}

// ---------------------------------------------------------------------------
// Single launch (proven R7 structure). Blocks 0..59: per-frame frontend ->
// Gx -> threadfence -> release flag. Block 60: stage w_hh (as f16 pairs)
// while frontends run, parallel-poll flags, then the scan.
// Scan (R7 layout, issue-thinned): lane j owns gate rows j and j+64. The
// h-broadcast is 16 readlanes of f16-PAIRS (packed per step via one DPP
// quad-swap + one v_cvt_pkrtz), the matvec is 32 v_dot2_f32_f16 (2 MACs
// each, f32 accumulate). Evidence R4/R5/R8: scan is issue-bound ~3 ns/instr,
// so -16 instrs/step is the lever.
// ---------------------------------------------------------------------------
__global__ __launch_bounds__(64) void fused_kernel(
    const float* __restrict__ x,
    const float* __restrict__ w00, const float* __restrict__ b00,
    const float* __restrict__ w01, const float* __restrict__ b01,
    const float* __restrict__ ln_g, const float* __restrict__ ln_b,
    const float* __restrict__ w_ih, const float* __restrict__ w_hh,
    const float* __restrict__ b_ih, const float* __restrict__ b_hh,
    const float* __restrict__ bn_g, const float* __restrict__ bn_b,
    const float* __restrict__ w10, const float* __restrict__ b10,
    const float* __restrict__ w11, const float* __restrict__ b11,
    const float* __restrict__ w12, const float* __restrict__ b12,
    float* __restrict__ Gx, unsigned* __restrict__ flags,
    float* __restrict__ out)
{
    __shared__ float smem[16324];
    const int j = threadIdx.x;

    if (blockIdx.x < 60) {
        // ------------------- frontend (proven round-1 body) -------------------
        const int t = blockIdx.x;
        float* w00s = smem;          // [63*63] rows stride 63 (conflict-free)
        float* w01s = smem + 3972;   // [64*63]
        float* wihT = smem + 8004;   // [64][128] transposed w_ih
        float* scr  = smem + 16196;  // [128]

        {
            const float4* g4 = (const float4*)w00;
            float4* s4 = (float4*)w00s;
            for (int i = j; i < 992; i += 64) s4[i] = g4[i];
            if (j == 0) w00s[3968] = w00[3968];
        }
        {
            const float4* g4 = (const float4*)w01;
            float4* s4 = (float4*)w01s;
            for (int i = j; i < 1008; i += 64) s4[i] = g4[i];
        }
        for (int r = j; r < 128; r += 64) {
            const float4* row = (const float4*)(w_ih + r * 64);
            #pragma unroll
            for (int q = 0; q < 16; q++) {
                float4 v = row[q];
                wihT[(4 * q + 0) * 128 + r] = v.x;
                wihT[(4 * q + 1) * 128 + r] = v.y;
                wihT[(4 * q + 2) * 128 + r] = v.z;
                wihT[(4 * q + 3) * 128 + r] = v.w;
            }
        }
        scr[j] = (j < 63) ? x[t * 63 + j] : 0.0f;
        __syncthreads();

        float f0 = 0.0f;
        if (j < 63) {
            float acc = b00[j];
            const float* wr = w00s + j * 63;
            #pragma unroll
            for (int k = 0; k < 63; k++) acc += scr[k] * wr[k];
            f0 = fmaxf(acc, 0.0f);
        }
        __syncthreads();
        scr[j] = f0;
        __syncthreads();

        float acc = b01[j];
        {
            const float* wr = w01s + j * 63;
            #pragma unroll
            for (int k = 0; k < 63; k++) acc += scr[k] * wr[k];
        }
        float f1 = fmaxf(acc, 0.0f);

        float s = f1, sq = f1 * f1;
        #pragma unroll
        for (int off = 32; off > 0; off >>= 1) {
            s  += __shfl_xor(s, off);
            sq += __shfl_xor(sq, off);
        }
        float mu  = s * (1.0f / 64.0f);
        float var = sq * (1.0f / 64.0f) - mu * mu;
        float f   = (f1 - mu) * rsqrtf(var + EPS) * ln_g[j] + ln_b[j];
        __syncthreads();
        scr[64 + j] = f;
        __syncthreads();

        float a0 = b_ih[j] + b_hh[j];
        float a1 = b_ih[j + 64] + b_hh[j + 64];
        #pragma unroll
        for (int k = 0; k < 64; k++) {
            float fk = scr[64 + k];
            a0 += fk * wihT[k * 128 + j];
            a1 += fk * wihT[k * 128 + 64 + j];
        }
        Gx[t * 128 + j]      = a0;
        Gx[t * 128 + 64 + j] = a1;

        __threadfence();
        __syncthreads();
        if (j == 0)
            __hip_atomic_store(&flags[t], MAGIC, __ATOMIC_RELEASE,
                               __HIP_MEMORY_SCOPE_AGENT);
        return;
    }

    // --------------------------- scan block (1 wave) ---------------------------
    float* gxs = smem;  // [61*128] (frame 60 = pad for prefetch)

    // Stage w_hh rows j and j+64 as f16 PAIRS (overlaps frontend).
    // wAh[q] = {W[j][2q], W[j][2q+1]}, wBh likewise for row j+64.
    h2v2 wAh[16], wBh[16];
    {
        const float4* r0 = (const float4*)(w_hh + j * 32);
        const float4* r1 = (const float4*)(w_hh + (j + 64) * 32);
        #pragma unroll
        for (int q = 0; q < 8; q++) {
            float4 a = r0[q];
            float4 b = r1[q];
            wAh[2 * q + 0] = __builtin_amdgcn_cvt_pkrtz(a.x, a.y);
            wAh[2 * q + 1] = __builtin_amdgcn_cvt_pkrtz(a.z, a.w);
            wBh[2 * q + 0] = __builtin_amdgcn_cvt_pkrtz(b.x, b.y);
            wBh[2 * q + 1] = __builtin_amdgcn_cvt_pkrtz(b.z, b.w);
        }
    }

    // Parallel poll: lane t watches flags[t] (relaxed agent load), one ballot
    // per sweep; single acquire for ordering. Poison != MAGIC re-arms replays.
    {
        bool done = (j >= 60);
        while (true) {
            if (!done)
                done = (__hip_atomic_load(&flags[j], __ATOMIC_RELAXED,
                                          __HIP_MEMORY_SCOPE_AGENT) == MAGIC);
            if (__ballot(done) == ~0ULL) break;
            __builtin_amdgcn_s_sleep(1);
        }
        (void)__hip_atomic_load(&flags[0], __ATOMIC_ACQUIRE,
                                __HIP_MEMORY_SCOPE_AGENT);
    }

    // stage Gx -> LDS (1920 float4) + zero pad frame
    {
        const float4* g4 = (const float4*)Gx;
        float4* s4 = (float4*)gxs;
        for (int i = j; i < 1920; i += 64) s4[i] = g4[i];
        gxs[7680 + j] = 0.0f;
        gxs[7744 + j] = 0.0f;
    }
    __syncthreads();

    const bool low = (j < 32);
    float c = 0.0f, hn = 0.0f;
    float gA = gxs[j], gB = gxs[64 + j];
    for (int t = 0; t < 60; t++) {
        // h lives on HIGH lanes (lane 32+m = h_m). Pack pairs: DPP quad_perm
        // [1,0,3,2] swaps lanes 2q<->2q+1 (VALU, no LDS pipe), then one
        // v_cvt_pkrtz packs {h_2q, h_2q+1} on even high lanes.
        int   hsw_i = __builtin_amdgcn_update_dpp(
                          0, __float_as_int(hn), 0xB1, 0xF, 0xF, true);
        h2v2  hpk   = __builtin_amdgcn_cvt_pkrtz(hn, __int_as_float(hsw_i));
        int   hpk_i = __builtin_bit_cast(int, hpk);

        // 16 readlanes (even high lanes) -> all 32 h values as f16 pairs
        int hh_i[16];
        #pragma unroll
        for (int k = 0; k < 16; k++) hh_i[k] = rdli(hpk_i, 32 + 2 * k);

        float aA0 = gA, aA1 = 0.f, aA2 = 0.f, aA3 = 0.f;
        float aB0 = gB, aB1 = 0.f, aB2 = 0.f, aB3 = 0.f;
        gA = gxs[(t + 1) * 128 + j];
        gB = gxs[(t + 1) * 128 + 64 + j];
        #pragma unroll
        for (int d = 0; d < 4; d++) {
            h2v2 h0 = __builtin_bit_cast(h2v2, hh_i[d]);
            h2v2 h1 = __builtin_bit_cast(h2v2, hh_i[4 + d]);
            h2v2 hx = __builtin_bit_cast(h2v2, hh_i[8 + d]);
            h2v2 h3 = __builtin_bit_cast(h2v2, hh_i[12 + d]);
            aA0 = fdot2(h0, wAh[d],      aA0);  aB0 = fdot2(h0, wBh[d],      aB0);
            aA1 = fdot2(h1, wAh[4 + d],  aA1);  aB1 = fdot2(h1, wBh[4 + d],  aB1);
            aA2 = fdot2(hx, wAh[8 + d],  aA2);  aB2 = fdot2(hx, wBh[8 + d],  aB2);
            aA3 = fdot2(h3, wAh[12 + d], aA3);  aB3 = fdot2(h3, wBh[12 + d], aB3);
        }
        float a0 = (aA0 + aA1) + (aA2 + aA3);  // low: i_m ; high: f_m
        float a1 = (aB0 + aB1) + (aB2 + aB3);  // low: g_m ; high: o_m

        // proven R7 nonlinearity block (shared exp for sigm(a1)/tanh(a1))
        float e1 = __expf(-a1);
        float sO = frcp(1.0f + e1);                 // high: sigm(o)
        float e2 = e1 * e1;                         // exp(-2*a1)
        float t1 = (1.0f - e2) * frcp(1.0f + e2);   // low: tanh(g)
        float s0 = fsigm(a0);                       // low: sigm(i); high: sigm(f)
        float own = s0 * (low ? t1 : c);
        c = xhalf_sum(own);          // sigm(i)tanh(g) + sigm(f)*c, all lanes
        hn = sO * ftanh(c);          // valid on high lanes
    }

    // Head (h read from HIGH lanes; lanes >=32 replicate rows 0..31)
    const float rs = rsqrtf(1.0f + EPS);
    const int ro = j & 31;
    float acc = b10[ro];
    #pragma unroll
    for (int k = 0; k < 32; k++) {
        float hkk = rdl32(hn, k);
        float hb = hkk * rs * bn_g[k] + bn_b[k];
        acc += w10[ro * 32 + k] * hb;
    }
    float o1 = fmaxf(acc, 0.0f);

    acc = b11[ro];
    #pragma unroll
    for (int k = 0; k < 32; k++)
        acc += w11[ro * 32 + k]
             * __int_as_float(__builtin_amdgcn_readlane(__float_as_int(o1), k));
    float o2 = fmaxf(acc, 0.0f);

    float a[4];
    #pragma unroll
    for (int r = 0; r < 4; r++) a[r] = b12[j + 64 * r];
    #pragma unroll
    for (int k = 0; k < 32; k++) {
        float hv = __int_as_float(__builtin_amdgcn_readlane(__float_as_int(o2), k));
        #pragma unroll
        for (int r = 0; r < 4; r++) a[r] += w12[(j + 64 * r) * 32 + k] * hv;
    }
    #pragma unroll
    for (int r = 0; r < 4; r++) out[j + 64 * r] = a[r];
}

extern "C" void kernel_launch(void* const* d_in, const int* in_sizes, int n_in,
                              void* d_out, int out_size, void* d_ws, size_t ws_size,
                              hipStream_t stream) {
    const float* x    = (const float*)d_in[0];
    const float* w00  = (const float*)d_in[1];
    const float* b00  = (const float*)d_in[2];
    const float* w01  = (const float*)d_in[3];
    const float* b01  = (const float*)d_in[4];
    const float* ln_g = (const float*)d_in[5];
    const float* ln_b = (const float*)d_in[6];
    const float* w_ih = (const float*)d_in[7];
    const float* w_hh = (const float*)d_in[8];
    const float* b_ih = (const float*)d_in[9];
    const float* b_hh = (const float*)d_in[10];
    const float* bn_g = (const float*)d_in[11];
    const float* bn_b = (const float*)d_in[12];
    const float* w10  = (const float*)d_in[13];
    const float* b10  = (const float*)d_in[14];
    const float* w11  = (const float*)d_in[15];
    const float* b11  = (const float*)d_in[16];
    const float* w12  = (const float*)d_in[17];
    const float* b12  = (const float*)d_in[18];
    float* out = (float*)d_out;
    float*    Gx    = (float*)d_ws;                       // 30,720 B
    unsigned* flags = (unsigned*)((char*)d_ws + 49152);   // 60 flags

    fused_kernel<<<61, 64, 0, stream>>>(x, w00, b00, w01, b01, ln_g, ln_b,
                                        w_ih, w_hh, b_ih, b_hh, bn_g, bn_b,
                                        w10, b10, w11, b11, w12, b12,
                                        Gx, flags, out);
}

// Round 11
// 124.289 us; speedup vs baseline: 1.0464x; 1.0144x over previous
//
#include <hip/hip_runtime.h>

#define EPS 1e-5f
#define MAGIC 0x5CA9F1A6u

// NOTE: amdgcn builtins (cvt_pkrtz, fdot2) use __fp16 vectors, not _Float16.
typedef __fp16 h2v2 __attribute__((ext_vector_type(2)));

// Fast reciprocal: single v_rcp_f32 (~1 ulp) instead of IEEE div sequence.
__device__ __forceinline__ float frcp(float x) { return __builtin_amdgcn_rcpf(x); }
__device__ __forceinline__ float fsigm(float x) { return frcp(1.0f + __expf(-x)); }
__device__ __forceinline__ float ftanh(float x) {
    float e = __expf(-2.0f * x);
    return (1.0f - e) * frcp(1.0f + e);
}
// uniform broadcast of lane k's value -> SGPR (k compile-time constant)
__device__ __forceinline__ int rdli(int v, int k) {
    return __builtin_amdgcn_readlane(v, k);
}
__device__ __forceinline__ float rdl32(float v, int k) {
    return __int_as_float(__builtin_amdgcn_readlane(__float_as_int(v), 32 + k));
}
// Sum of lane m and lane m+32's values, replicated to both halves (semantics-
// agnostic use of permlane32_swap: sum of both outputs = x[m]+x[m+32]).
__device__ __forceinline__ float xhalf_sum(float x) {
#if __has_builtin(__builtin_amdgcn_permlane32_swap)
    auto r = __builtin_amdgcn_permlane32_swap(__float_as_uint(x),
                                              __float_as_uint(x), false, false);
    return __uint_as_float(r[0]) + __uint_as_float(r[1]);
#else
    return x + __shfl_xor(x, 32);
#endif
}
// 2-way f16 dot with f32 accumulate: v_dot2_f32_f16 (2 MACs / instruction)
__device__ __forceinline__ float fdot2(h2v2 a, h2v2 b, float c) {
#if __has_builtin(__builtin_amdgcn_fdot2)
    return __builtin_amdgcn_fdot2(a, b, c, false);
#else
    return c + (float)a.x * (float)b.x + (float)a.y * (float)b.y;
#endif
}

// ---------------------------------------------------------------------------
// Single launch (proven R7/R10 structure). Blocks 0..59: per-frame frontend
// -> Gx -> threadfence -> release flag. Block 60: stage w_hh (f16 pairs)
// while frontends run, parallel-poll flags, then the scan.
// Scan (R10 + register-resident Gx): the 60-step loop is chunked 5 x 12;
// each chunk bulk-loads 24 gate inputs into VGPRs at chunk top, so the step
// body has ZERO LDS ops -- removes any per-step lgkmcnt wait from the
// serial chain (R10 post-mortem: scan is latency-bound; per-step LDS reads
// are the last untested chain element).
// ---------------------------------------------------------------------------
__global__ __launch_bounds__(64) void fused_kernel(
    const float* __restrict__ x,
    const float* __restrict__ w00, const float* __restrict__ b00,
    const float* __restrict__ w01, const float* __restrict__ b01,
    const float* __restrict__ ln_g, const float* __restrict__ ln_b,
    const float* __restrict__ w_ih, const float* __restrict__ w_hh,
    const float* __restrict__ b_ih, const float* __restrict__ b_hh,
    const float* __restrict__ bn_g, const float* __restrict__ bn_b,
    const float* __restrict__ w10, const float* __restrict__ b10,
    const float* __restrict__ w11, const float* __restrict__ b11,
    const float* __restrict__ w12, const float* __restrict__ b12,
    float* __restrict__ Gx, unsigned* __restrict__ flags,
    float* __restrict__ out)
{
    __shared__ float smem[16324];
    const int j = threadIdx.x;

    if (blockIdx.x < 60) {
        // ------------------- frontend (proven round-1 body) -------------------
        const int t = blockIdx.x;
        float* w00s = smem;          // [63*63] rows stride 63 (conflict-free)
        float* w01s = smem + 3972;   // [64*63]
        float* wihT = smem + 8004;   // [64][128] transposed w_ih
        float* scr  = smem + 16196;  // [128]

        {
            const float4* g4 = (const float4*)w00;
            float4* s4 = (float4*)w00s;
            for (int i = j; i < 992; i += 64) s4[i] = g4[i];
            if (j == 0) w00s[3968] = w00[3968];
        }
        {
            const float4* g4 = (const float4*)w01;
            float4* s4 = (float4*)w01s;
            for (int i = j; i < 1008; i += 64) s4[i] = g4[i];
        }
        for (int r = j; r < 128; r += 64) {
            const float4* row = (const float4*)(w_ih + r * 64);
            #pragma unroll
            for (int q = 0; q < 16; q++) {
                float4 v = row[q];
                wihT[(4 * q + 0) * 128 + r] = v.x;
                wihT[(4 * q + 1) * 128 + r] = v.y;
                wihT[(4 * q + 2) * 128 + r] = v.z;
                wihT[(4 * q + 3) * 128 + r] = v.w;
            }
        }
        scr[j] = (j < 63) ? x[t * 63 + j] : 0.0f;
        __syncthreads();

        float f0 = 0.0f;
        if (j < 63) {
            float acc = b00[j];
            const float* wr = w00s + j * 63;
            #pragma unroll
            for (int k = 0; k < 63; k++) acc += scr[k] * wr[k];
            f0 = fmaxf(acc, 0.0f);
        }
        __syncthreads();
        scr[j] = f0;
        __syncthreads();

        float acc = b01[j];
        {
            const float* wr = w01s + j * 63;
            #pragma unroll
            for (int k = 0; k < 63; k++) acc += scr[k] * wr[k];
        }
        float f1 = fmaxf(acc, 0.0f);

        float s = f1, sq = f1 * f1;
        #pragma unroll
        for (int off = 32; off > 0; off >>= 1) {
            s  += __shfl_xor(s, off);
            sq += __shfl_xor(sq, off);
        }
        float mu  = s * (1.0f / 64.0f);
        float var = sq * (1.0f / 64.0f) - mu * mu;
        float f   = (f1 - mu) * rsqrtf(var + EPS) * ln_g[j] + ln_b[j];
        __syncthreads();
        scr[64 + j] = f;
        __syncthreads();

        float a0 = b_ih[j] + b_hh[j];
        float a1 = b_ih[j + 64] + b_hh[j + 64];
        #pragma unroll
        for (int k = 0; k < 64; k++) {
            float fk = scr[64 + k];
            a0 += fk * wihT[k * 128 + j];
            a1 += fk * wihT[k * 128 + 64 + j];
        }
        Gx[t * 128 + j]      = a0;
        Gx[t * 128 + 64 + j] = a1;

        __threadfence();
        __syncthreads();
        if (j == 0)
            __hip_atomic_store(&flags[t], MAGIC, __ATOMIC_RELEASE,
                               __HIP_MEMORY_SCOPE_AGENT);
        return;
    }

    // --------------------------- scan block (1 wave) ---------------------------
    float* gxs = smem;  // [60*128]

    // Stage w_hh rows j and j+64 as f16 PAIRS (overlaps frontend).
    h2v2 wAh[16], wBh[16];
    {
        const float4* r0 = (const float4*)(w_hh + j * 32);
        const float4* r1 = (const float4*)(w_hh + (j + 64) * 32);
        #pragma unroll
        for (int q = 0; q < 8; q++) {
            float4 a = r0[q];
            float4 b = r1[q];
            wAh[2 * q + 0] = __builtin_amdgcn_cvt_pkrtz(a.x, a.y);
            wAh[2 * q + 1] = __builtin_amdgcn_cvt_pkrtz(a.z, a.w);
            wBh[2 * q + 0] = __builtin_amdgcn_cvt_pkrtz(b.x, b.y);
            wBh[2 * q + 1] = __builtin_amdgcn_cvt_pkrtz(b.z, b.w);
        }
    }

    // Parallel poll: lane t watches flags[t] (relaxed agent load), one ballot
    // per sweep; single acquire for ordering. Poison != MAGIC re-arms replays.
    {
        bool done = (j >= 60);
        while (true) {
            if (!done)
                done = (__hip_atomic_load(&flags[j], __ATOMIC_RELAXED,
                                          __HIP_MEMORY_SCOPE_AGENT) == MAGIC);
            if (__ballot(done) == ~0ULL) break;
            __builtin_amdgcn_s_sleep(1);
        }
        (void)__hip_atomic_load(&flags[0], __ATOMIC_ACQUIRE,
                                __HIP_MEMORY_SCOPE_AGENT);
    }

    // stage Gx -> LDS (1920 float4)
    {
        const float4* g4 = (const float4*)Gx;
        float4* s4 = (float4*)gxs;
        for (int i = j; i < 1920; i += 64) s4[i] = g4[i];
    }
    __syncthreads();

    const bool low = (j < 32);
    float c = 0.0f, hn = 0.0f;
    #pragma unroll 1   // keep outer rolled: 5x ~9KB inner would blow L1I
    for (int c0 = 0; c0 < 5; c0++) {
        // chunk-top bulk refill: 24 LDS reads, latency exposed once per 12
        // steps instead of every step
        float gAr[12], gBr[12];
        #pragma unroll
        for (int i = 0; i < 12; i++) {
            gAr[i] = gxs[(c0 * 12 + i) * 128 + j];
            gBr[i] = gxs[(c0 * 12 + i) * 128 + 64 + j];
        }
        #pragma unroll
        for (int i = 0; i < 12; i++) {
            // h lives on HIGH lanes (lane 32+m = h_m). Pack pairs: DPP
            // quad_perm [1,0,3,2] swaps lanes 2q<->2q+1 (VALU, no LDS pipe),
            // then one v_cvt_pkrtz packs {h_2q, h_2q+1} on even high lanes.
            int   hsw_i = __builtin_amdgcn_update_dpp(
                              0, __float_as_int(hn), 0xB1, 0xF, 0xF, true);
            h2v2  hpk   = __builtin_amdgcn_cvt_pkrtz(hn, __int_as_float(hsw_i));
            int   hpk_i = __builtin_bit_cast(int, hpk);

            // 16 readlanes (even high lanes) -> all 32 h values as f16 pairs
            int hh_i[16];
            #pragma unroll
            for (int k = 0; k < 16; k++) hh_i[k] = rdli(hpk_i, 32 + 2 * k);

            float aA0 = gAr[i], aA1 = 0.f, aA2 = 0.f, aA3 = 0.f;
            float aB0 = gBr[i], aB1 = 0.f, aB2 = 0.f, aB3 = 0.f;
            #pragma unroll
            for (int d = 0; d < 4; d++) {
                h2v2 h0 = __builtin_bit_cast(h2v2, hh_i[d]);
                h2v2 h1 = __builtin_bit_cast(h2v2, hh_i[4 + d]);
                h2v2 hx = __builtin_bit_cast(h2v2, hh_i[8 + d]);
                h2v2 h3 = __builtin_bit_cast(h2v2, hh_i[12 + d]);
                aA0 = fdot2(h0, wAh[d],      aA0);  aB0 = fdot2(h0, wBh[d],      aB0);
                aA1 = fdot2(h1, wAh[4 + d],  aA1);  aB1 = fdot2(h1, wBh[4 + d],  aB1);
                aA2 = fdot2(hx, wAh[8 + d],  aA2);  aB2 = fdot2(hx, wBh[8 + d],  aB2);
                aA3 = fdot2(h3, wAh[12 + d], aA3);  aB3 = fdot2(h3, wBh[12 + d], aB3);
            }
            float a0 = (aA0 + aA1) + (aA2 + aA3);  // low: i_m ; high: f_m
            float a1 = (aB0 + aB1) + (aB2 + aB3);  // low: g_m ; high: o_m

            // shared-exp nonlinearity block (proven R7)
            float e1 = __expf(-a1);
            float sO = frcp(1.0f + e1);                 // high: sigm(o)
            float e2 = e1 * e1;                         // exp(-2*a1)
            float t1 = (1.0f - e2) * frcp(1.0f + e2);   // low: tanh(g)
            float s0 = fsigm(a0);                       // low: sigm(i); high: sigm(f)
            float own = s0 * (low ? t1 : c);
            c = xhalf_sum(own);          // sigm(i)tanh(g) + sigm(f)*c
            hn = sO * ftanh(c);          // valid on high lanes
        }
    }

    // Head (h read from HIGH lanes; lanes >=32 replicate rows 0..31)
    const float rs = rsqrtf(1.0f + EPS);
    const int ro = j & 31;
    float acc = b10[ro];
    #pragma unroll
    for (int k = 0; k < 32; k++) {
        float hkk = rdl32(hn, k);
        float hb = hkk * rs * bn_g[k] + bn_b[k];
        acc += w10[ro * 32 + k] * hb;
    }
    float o1 = fmaxf(acc, 0.0f);

    acc = b11[ro];
    #pragma unroll
    for (int k = 0; k < 32; k++)
        acc += w11[ro * 32 + k]
             * __int_as_float(__builtin_amdgcn_readlane(__float_as_int(o1), k));
    float o2 = fmaxf(acc, 0.0f);

    float a[4];
    #pragma unroll
    for (int r = 0; r < 4; r++) a[r] = b12[j + 64 * r];
    #pragma unroll
    for (int k = 0; k < 32; k++) {
        float hv = __int_as_float(__builtin_amdgcn_readlane(__float_as_int(o2), k));
        #pragma unroll
        for (int r = 0; r < 4; r++) a[r] += w12[(j + 64 * r) * 32 + k] * hv;
    }
    #pragma unroll
    for (int r = 0; r < 4; r++) out[j + 64 * r] = a[r];
}

extern "C" void kernel_launch(void* const* d_in, const int* in_sizes, int n_in,
                              void* d_out, int out_size, void* d_ws, size_t ws_size,
                              hipStream_t stream) {
    const float* x    = (const float*)d_in[0];
    const float* w00  = (const float*)d_in[1];
    const float* b00  = (const float*)d_in[2];
    const float* w01  = (const float*)d_in[3];
    const float* b01  = (const float*)d_in[4];
    const float* ln_g = (const float*)d_in[5];
    const float* ln_b = (const float*)d_in[6];
    const float* w_ih = (const float*)d_in[7];
    const float* w_hh = (const float*)d_in[8];
    const float* b_ih = (const float*)d_in[9];
    const float* b_hh = (const float*)d_in[10];
    const float* bn_g = (const float*)d_in[11];
    const float* bn_b = (const float*)d_in[12];
    const float* w10  = (const float*)d_in[13];
    const float* b10  = (const float*)d_in[14];
    const float* w11  = (const float*)d_in[15];
    const float* b11  = (const float*)d_in[16];
    const float* w12  = (const float*)d_in[17];
    const float* b12  = (const float*)d_in[18];
    float* out = (float*)d_out;
    float*    Gx    = (float*)d_ws;                       // 30,720 B
    unsigned* flags = (unsigned*)((char*)d_ws + 49152);   // 60 flags

    fused_kernel<<<61, 64, 0, stream>>>(x, w00, b00, w01, b01, ln_g, ln_b,
                                        w_ih, w_hh, b_ih, b_hh, bn_g, bn_b,
                                        w10, b10, w11, b11, w12, b12,
                                        Gx, flags, out);
}

// Round 12
// 107.749 us; speedup vs baseline: 1.2071x; 1.1535x over previous
//
#include <hip/hip_runtime.h>

#define EPS 1e-5f
#define MAGIC 0x5CA9F1A6u

// NOTE: amdgcn builtins (cvt_pkrtz, fdot2) use __fp16 vectors, not _Float16.
typedef __fp16 h2v2 __attribute__((ext_vector_type(2)));

// Fast reciprocal: single v_rcp_f32 (~1 ulp) instead of IEEE div sequence.
__device__ __forceinline__ float frcp(float x) { return __builtin_amdgcn_rcpf(x); }
__device__ __forceinline__ float fsigm(float x) { return frcp(1.0f + __expf(-x)); }
__device__ __forceinline__ float ftanh(float x) {
    float e = __expf(-2.0f * x);
    return (1.0f - e) * frcp(1.0f + e);
}
// uniform broadcast of lane k's value -> SGPR (k compile-time constant)
__device__ __forceinline__ int rdli(int v, int k) {
    return __builtin_amdgcn_readlane(v, k);
}
__device__ __forceinline__ float rdl32(float v, int k) {
    return __int_as_float(__builtin_amdgcn_readlane(__float_as_int(v), 32 + k));
}
// Sum of lane m and lane m+32's values, replicated to both halves (semantics-
// agnostic use of permlane32_swap: sum of both outputs = x[m]+x[m+32]).
__device__ __forceinline__ float xhalf_sum(float x) {
#if __has_builtin(__builtin_amdgcn_permlane32_swap)
    auto r = __builtin_amdgcn_permlane32_swap(__float_as_uint(x),
                                              __float_as_uint(x), false, false);
    return __uint_as_float(r[0]) + __uint_as_float(r[1]);
#else
    return x + __shfl_xor(x, 32);
#endif
}
// 2-way f16 dot with f32 accumulate: v_dot2_f32_f16 (2 MACs / instruction)
__device__ __forceinline__ float fdot2(h2v2 a, h2v2 b, float c) {
#if __has_builtin(__builtin_amdgcn_fdot2)
    return __builtin_amdgcn_fdot2(a, b, c, false);
#else
    return c + (float)a.x * (float)b.x + (float)a.y * (float)b.y;
#endif
}

// ---------------------------------------------------------------------------
// Single launch, STAGING-FREE (R12): post-R11 evidence says the scan body is
// no longer binding; the remaining cost is prologue staging latency.
// Blocks 0..59 (frontend): weights read DIRECTLY from global in the dot
// loops (lane j reads row j; same rows across blocks -> L2/IC broadcast;
// identical k-order -> bitwise-identical results). No w00s/w01s/wihT LDS
// stage, no transpose, 2 fewer barriers. LDS = 128 floats (activations).
// Block 60 (scan): NO Gx->LDS stage; R11's 12-step chunk refills load
// straight from global (lane-consecutive = coalesced, one L2 latency per
// chunk). Scan body/poll/head byte-identical to R11.
// ---------------------------------------------------------------------------
__global__ __launch_bounds__(64) void fused_kernel(
    const float* __restrict__ x,
    const float* __restrict__ w00, const float* __restrict__ b00,
    const float* __restrict__ w01, const float* __restrict__ b01,
    const float* __restrict__ ln_g, const float* __restrict__ ln_b,
    const float* __restrict__ w_ih, const float* __restrict__ w_hh,
    const float* __restrict__ b_ih, const float* __restrict__ b_hh,
    const float* __restrict__ bn_g, const float* __restrict__ bn_b,
    const float* __restrict__ w10, const float* __restrict__ b10,
    const float* __restrict__ w11, const float* __restrict__ b11,
    const float* __restrict__ w12, const float* __restrict__ b12,
    float* __restrict__ Gx, unsigned* __restrict__ flags,
    float* __restrict__ out)
{
    __shared__ float scr[128];
    const int j = threadIdx.x;

    if (blockIdx.x < 60) {
        // ------------------- frontend (staging-free) -------------------
        const int t = blockIdx.x;

        scr[j] = (j < 63) ? x[t * 63 + j] : 0.0f;
        __syncthreads();

        // f0 = relu(x . w00 row j + b00[j])  -- row read direct from global
        float f0 = 0.0f;
        if (j < 63) {
            const float* wr = w00 + j * 63;
            float acc = b00[j];
            #pragma unroll
            for (int k = 0; k < 63; k++) acc += scr[k] * wr[k];
            f0 = fmaxf(acc, 0.0f);
        }
        __syncthreads();
        scr[j] = f0;
        __syncthreads();

        // f1 = relu(f0 . w01 row j + b01[j])
        float acc = b01[j];
        {
            const float* wr = w01 + j * 63;
            #pragma unroll
            for (int k = 0; k < 63; k++) acc += scr[k] * wr[k];
        }
        float f1 = fmaxf(acc, 0.0f);

        // LayerNorm over the 64 lanes (wave butterfly)
        float s = f1, sq = f1 * f1;
        #pragma unroll
        for (int off = 32; off > 0; off >>= 1) {
            s  += __shfl_xor(s, off);
            sq += __shfl_xor(sq, off);
        }
        float mu  = s * (1.0f / 64.0f);
        float var = sq * (1.0f / 64.0f) - mu * mu;
        float f   = (f1 - mu) * rsqrtf(var + EPS) * ln_g[j] + ln_b[j];
        __syncthreads();
        scr[64 + j] = f;
        __syncthreads();

        // gate projection: rows j and j+64 of w_ih, direct from global,
        // same k-order as the old wihT path -> bitwise identical
        float a0 = b_ih[j] + b_hh[j];
        float a1 = b_ih[j + 64] + b_hh[j + 64];
        const float* wi0 = w_ih + j * 64;
        const float* wi1 = w_ih + (j + 64) * 64;
        #pragma unroll
        for (int k = 0; k < 64; k++) {
            float fk = scr[64 + k];
            a0 += fk * wi0[k];
            a1 += fk * wi1[k];
        }
        Gx[t * 128 + j]      = a0;
        Gx[t * 128 + 64 + j] = a1;

        __threadfence();
        __syncthreads();
        if (j == 0)
            __hip_atomic_store(&flags[t], MAGIC, __ATOMIC_RELEASE,
                               __HIP_MEMORY_SCOPE_AGENT);
        return;
    }

    // --------------------------- scan block (1 wave) ---------------------------
    // Stage w_hh rows j and j+64 as f16 PAIRS (overlaps frontend).
    h2v2 wAh[16], wBh[16];
    {
        const float4* r0 = (const float4*)(w_hh + j * 32);
        const float4* r1 = (const float4*)(w_hh + (j + 64) * 32);
        #pragma unroll
        for (int q = 0; q < 8; q++) {
            float4 a = r0[q];
            float4 b = r1[q];
            wAh[2 * q + 0] = __builtin_amdgcn_cvt_pkrtz(a.x, a.y);
            wAh[2 * q + 1] = __builtin_amdgcn_cvt_pkrtz(a.z, a.w);
            wBh[2 * q + 0] = __builtin_amdgcn_cvt_pkrtz(b.x, b.y);
            wBh[2 * q + 1] = __builtin_amdgcn_cvt_pkrtz(b.z, b.w);
        }
    }

    // Parallel poll: lane t watches flags[t] (relaxed agent load), one ballot
    // per sweep; single acquire for ordering. Poison != MAGIC re-arms replays.
    {
        bool done = (j >= 60);
        while (true) {
            if (!done)
                done = (__hip_atomic_load(&flags[j], __ATOMIC_RELAXED,
                                          __HIP_MEMORY_SCOPE_AGENT) == MAGIC);
            if (__ballot(done) == ~0ULL) break;
            __builtin_amdgcn_s_sleep(1);
        }
        (void)__hip_atomic_load(&flags[0], __ATOMIC_ACQUIRE,
                                __HIP_MEMORY_SCOPE_AGENT);
    }

    const bool low = (j < 32);
    float c = 0.0f, hn = 0.0f;
    #pragma unroll 1   // keep outer rolled: 5x ~9KB inner would blow L1I
    for (int c0 = 0; c0 < 5; c0++) {
        // chunk-top bulk refill DIRECT from global: lane-consecutive
        // addresses -> coalesced; one latency exposure per 12 steps
        float gAr[12], gBr[12];
        #pragma unroll
        for (int i = 0; i < 12; i++) {
            gAr[i] = Gx[(c0 * 12 + i) * 128 + j];
            gBr[i] = Gx[(c0 * 12 + i) * 128 + 64 + j];
        }
        #pragma unroll
        for (int i = 0; i < 12; i++) {
            // h lives on HIGH lanes (lane 32+m = h_m). Pack pairs: DPP
            // quad_perm [1,0,3,2] swaps lanes 2q<->2q+1 (VALU, no LDS pipe),
            // then one v_cvt_pkrtz packs {h_2q, h_2q+1} on even high lanes.
            int   hsw_i = __builtin_amdgcn_update_dpp(
                              0, __float_as_int(hn), 0xB1, 0xF, 0xF, true);
            h2v2  hpk   = __builtin_amdgcn_cvt_pkrtz(hn, __int_as_float(hsw_i));
            int   hpk_i = __builtin_bit_cast(int, hpk);

            // 16 readlanes (even high lanes) -> all 32 h values as f16 pairs
            int hh_i[16];
            #pragma unroll
            for (int k = 0; k < 16; k++) hh_i[k] = rdli(hpk_i, 32 + 2 * k);

            float aA0 = gAr[i], aA1 = 0.f, aA2 = 0.f, aA3 = 0.f;
            float aB0 = gBr[i], aB1 = 0.f, aB2 = 0.f, aB3 = 0.f;
            #pragma unroll
            for (int d = 0; d < 4; d++) {
                h2v2 h0 = __builtin_bit_cast(h2v2, hh_i[d]);
                h2v2 h1 = __builtin_bit_cast(h2v2, hh_i[4 + d]);
                h2v2 hx = __builtin_bit_cast(h2v2, hh_i[8 + d]);
                h2v2 h3 = __builtin_bit_cast(h2v2, hh_i[12 + d]);
                aA0 = fdot2(h0, wAh[d],      aA0);  aB0 = fdot2(h0, wBh[d],      aB0);
                aA1 = fdot2(h1, wAh[4 + d],  aA1);  aB1 = fdot2(h1, wBh[4 + d],  aB1);
                aA2 = fdot2(hx, wAh[8 + d],  aA2);  aB2 = fdot2(hx, wBh[8 + d],  aB2);
                aA3 = fdot2(h3, wAh[12 + d], aA3);  aB3 = fdot2(h3, wBh[12 + d], aB3);
            }
            float a0 = (aA0 + aA1) + (aA2 + aA3);  // low: i_m ; high: f_m
            float a1 = (aB0 + aB1) + (aB2 + aB3);  // low: g_m ; high: o_m

            // shared-exp nonlinearity block (proven R7)
            float e1 = __expf(-a1);
            float sO = frcp(1.0f + e1);                 // high: sigm(o)
            float e2 = e1 * e1;                         // exp(-2*a1)
            float t1 = (1.0f - e2) * frcp(1.0f + e2);   // low: tanh(g)
            float s0 = fsigm(a0);                       // low: sigm(i); high: sigm(f)
            float own = s0 * (low ? t1 : c);
            c = xhalf_sum(own);          // sigm(i)tanh(g) + sigm(f)*c
            hn = sO * ftanh(c);          // valid on high lanes
        }
    }

    // Head (h read from HIGH lanes; lanes >=32 replicate rows 0..31)
    const float rs = rsqrtf(1.0f + EPS);
    const int ro = j & 31;
    float acc = b10[ro];
    #pragma unroll
    for (int k = 0; k < 32; k++) {
        float hkk = rdl32(hn, k);
        float hb = hkk * rs * bn_g[k] + bn_b[k];
        acc += w10[ro * 32 + k] * hb;
    }
    float o1 = fmaxf(acc, 0.0f);

    acc = b11[ro];
    #pragma unroll
    for (int k = 0; k < 32; k++)
        acc += w11[ro * 32 + k]
             * __int_as_float(__builtin_amdgcn_readlane(__float_as_int(o1), k));
    float o2 = fmaxf(acc, 0.0f);

    float a[4];
    #pragma unroll
    for (int r = 0; r < 4; r++) a[r] = b12[j + 64 * r];
    #pragma unroll
    for (int k = 0; k < 32; k++) {
        float hv = __int_as_float(__builtin_amdgcn_readlane(__float_as_int(o2), k));
        #pragma unroll
        for (int r = 0; r < 4; r++) a[r] += w12[(j + 64 * r) * 32 + k] * hv;
    }
    #pragma unroll
    for (int r = 0; r < 4; r++) out[j + 64 * r] = a[r];
}

extern "C" void kernel_launch(void* const* d_in, const int* in_sizes, int n_in,
                              void* d_out, int out_size, void* d_ws, size_t ws_size,
                              hipStream_t stream) {
    const float* x    = (const float*)d_in[0];
    const float* w00  = (const float*)d_in[1];
    const float* b00  = (const float*)d_in[2];
    const float* w01  = (const float*)d_in[3];
    const float* b01  = (const float*)d_in[4];
    const float* ln_g = (const float*)d_in[5];
    const float* ln_b = (const float*)d_in[6];
    const float* w_ih = (const float*)d_in[7];
    const float* w_hh = (const float*)d_in[8];
    const float* b_ih = (const float*)d_in[9];
    const float* b_hh = (const float*)d_in[10];
    const float* bn_g = (const float*)d_in[11];
    const float* bn_b = (const float*)d_in[12];
    const float* w10  = (const float*)d_in[13];
    const float* b10  = (const float*)d_in[14];
    const float* w11  = (const float*)d_in[15];
    const float* b11  = (const float*)d_in[16];
    const float* w12  = (const float*)d_in[17];
    const float* b12  = (const float*)d_in[18];
    float* out = (float*)d_out;
    float*    Gx    = (float*)d_ws;                       // 30,720 B
    unsigned* flags = (unsigned*)((char*)d_ws + 49152);   // 60 flags

    fused_kernel<<<61, 64, 0, stream>>>(x, w00, b00, w01, b01, ln_g, ln_b,
                                        w_ih, w_hh, b_ih, b_hh, bn_g, bn_b,
                                        w10, b10, w11, b11, w12, b12,
                                        Gx, flags, out);
}